// Round 3
// baseline (99.405 us; speedup 1.0000x reference)
//
#include <hip/hip_runtime.h>

#define NR 1024
#define ROWS 4
#define NBLK (NR / ROWS)   // 256 blocks = 1 per CU
#define NTHR 1024

// ---------------- cross-lane helpers (reduction over the 16 h-lanes) ----------
__device__ __forceinline__ float xor1v(float v) {  // partner lane^1 via DPP quad_perm(1,0,3,2)
    return __int_as_float(__builtin_amdgcn_mov_dpp(__float_as_int(v), 0xB1, 0xF, 0xF, true));
}
__device__ __forceinline__ float xor2v(float v) {  // partner lane^2 via DPP quad_perm(2,3,0,1)
    return __int_as_float(__builtin_amdgcn_mov_dpp(__float_as_int(v), 0x4E, 0xF, 0xF, true));
}
__device__ __forceinline__ float xor4v(float v) {  // ds_swizzle xor 4
    return __int_as_float(__builtin_amdgcn_ds_swizzle(__float_as_int(v), 0x101F));
}
__device__ __forceinline__ float xor8v(float v) {  // ds_swizzle xor 8
    return __int_as_float(__builtin_amdgcn_ds_swizzle(__float_as_int(v), 0x201F));
}

// ---------------- K1: partial column sums of x2 / x2^2 into disjoint ws slots
__global__ __launch_bounds__(256) void stats_kernel(const float* __restrict__ x2,
                                                    float* __restrict__ ws,
                                                    float* __restrict__ out) {
    int tid = threadIdx.x;
    int d = tid & 127;
    int g = tid >> 7;
    int row0 = blockIdx.x * 128 + g;
    float s = 0.f, s2 = 0.f;
#pragma unroll 8
    for (int i = 0; i < 64; i++) {
        float v = x2[(row0 + 2 * i) * 128 + d];
        s += v;
        s2 += v * v;
    }
    __shared__ float sh[256];
    __shared__ float sh2[256];
    sh[tid] = s;
    sh2[tid] = s2;
    __syncthreads();
    if (g == 0) {
        ws[blockIdx.x * 256 + d]       = sh[tid] + sh[tid + 128];
        ws[blockIdx.x * 256 + 128 + d] = sh2[tid] + sh2[tid + 128];
    }
    if (blockIdx.x == 0 && tid == 0) out[0] = 0.f;
}

// ---------------- fused layer: thread = (4 cols c4.., 4 rows, 16 interleaved k's)
// x from LDS: 16 ds_read_b128, <=2-way bank alias (free). W from global: 16 float4,
// read exactly once per block. 16-way k-split reduced in-register (DPP + 2 swizzles).
__device__ __forceinline__ void layer(const float* __restrict__ in_lds,
                                      const float* __restrict__ W,
                                      const float* __restrict__ b,
                                      float* __restrict__ out_lds,
                                      int h, int c4, int act) {
    float acc[16];
#pragma unroll
    for (int t = 0; t < 16; t++) acc[t] = 0.f;
    const float4* in4 = (const float4*)in_lds;
#pragma unroll
    for (int j = 0; j < 4; j++) {
        int k0 = h * 4 + j * 64;           // interleaved k-chunks: h, h+16, h+32, h+48
        float4 w[4];
        w[0] = *(const float4*)(W + (k0 + 0) * 256 + c4);
        w[1] = *(const float4*)(W + (k0 + 1) * 256 + c4);
        w[2] = *(const float4*)(W + (k0 + 2) * 256 + c4);
        w[3] = *(const float4*)(W + (k0 + 3) * 256 + c4);
        float4 xr[4];
        xr[0] = in4[0 * 64 + h + j * 16];
        xr[1] = in4[1 * 64 + h + j * 16];
        xr[2] = in4[2 * 64 + h + j * 16];
        xr[3] = in4[3 * 64 + h + j * 16];
#pragma unroll
        for (int r = 0; r < 4; r++) {
#pragma unroll
            for (int c = 0; c < 4; c++) {
                float a = acc[r * 4 + c];
                a = fmaf(((const float*)&xr[r])[0], ((const float*)&w[0])[c], a);
                a = fmaf(((const float*)&xr[r])[1], ((const float*)&w[1])[c], a);
                a = fmaf(((const float*)&xr[r])[2], ((const float*)&w[2])[c], a);
                a = fmaf(((const float*)&xr[r])[3], ((const float*)&w[3])[c], a);
                acc[r * 4 + c] = a;
            }
        }
    }
    // register-halving butterfly over the 16 h-lanes.
    // stage selects index bit: xor1->bit3, xor2->bit2, xor4->bit1, xor8->bit0
    float r8[8];
#pragma unroll
    for (int t = 0; t < 8; t++) {
        float lo = acc[t] + xor1v(acc[t]);
        float hi = acc[t + 8] + xor1v(acc[t + 8]);
        r8[t] = (h & 1) ? hi : lo;
    }
    float r4[4];
#pragma unroll
    for (int t = 0; t < 4; t++) {
        float lo = r8[t] + xor2v(r8[t]);
        float hi = r8[t + 4] + xor2v(r8[t + 4]);
        r4[t] = (h & 2) ? hi : lo;
    }
    float r2[2];
#pragma unroll
    for (int t = 0; t < 2; t++) {
        float lo = r4[t] + xor4v(r4[t]);
        float hi = r4[t + 2] + xor4v(r4[t + 2]);
        r2[t] = (h & 4) ? hi : lo;
    }
    float lo = r2[0] + xor8v(r2[0]);
    float hi = r2[1] + xor8v(r2[1]);
    float sum = (h & 8) ? hi : lo;
    // lane h holds acc index t = (h0<<3)|(h1<<2)|(h2<<1)|h3  -> r=t>>2, cc=t&3
    int r_out = ((h & 1) << 1) | ((h >> 1) & 1);
    int c_out = (((h >> 2) & 1) << 1) | ((h >> 3) & 1);
    float v = sum + b[c4 + c_out];
    v = act ? tanhf(v) : fmaxf(v, 0.f);
    out_lds[r_out * 256 + c4 + c_out] = v;
    __syncthreads();
}

// ---------------- K2: fused 3-layer MLP + CLUB contribution + reduction
__global__ __launch_bounds__(1024, 4) void club_kernel(
    const float* __restrict__ x1, const float* __restrict__ x2,
    const float* __restrict__ W1, const float* __restrict__ b1,
    const float* __restrict__ W2, const float* __restrict__ b2,
    const float* __restrict__ W3, const float* __restrict__ b3,
    const float* __restrict__ part, float* __restrict__ out) {
    __shared__ float bufA[ROWS * 256];
    __shared__ float bufB[ROWS * 256];
    __shared__ float x2s[ROWS * 128];
    __shared__ float stat[256];
    __shared__ double dred[16];

    int tid = threadIdx.x;
    int lane = tid & 63, wv = tid >> 6;
    int h = lane & 15;
    int c4 = (wv * 4 + (lane >> 4)) * 4;   // 4 consecutive columns per thread
    int row0 = blockIdx.x * ROWS;

    // prologue: stage x1 (4x256), x2 (4x128); reduce the 8 stats partials
    if (tid < 256) {
        ((float4*)bufA)[tid] = ((const float4*)(x1 + row0 * 256))[tid];
    } else if (tid < 384) {
        ((float4*)x2s)[tid - 256] = ((const float4*)(x2 + row0 * 128))[tid - 256];
    } else if (tid >= 512 && tid < 768) {
        int t = tid - 512;
        float s = 0.f;
#pragma unroll
        for (int p = 0; p < 8; p++) s += part[p * 256 + t];
        stat[t] = s * (1.f / 1024.f);
    }
    __syncthreads();

    layer(bufA, W1, b1, bufB, h, c4, 0);   // h1 = relu(x1@W1+b1)
    layer(bufB, W2, b2, bufA, h, c4, 0);   // h2 = relu(h1@W2+b2)
    layer(bufA, W3, b3, bufB, h, c4, 1);   // g  = tanh(h2@W3+b3)

    // contribution: pos-neg = -0.5*exp(-lv)*( x2^2 - mxsq - 2*mu*(x2 - mx) )
    double p = 0.0;
    if (tid < 512) {
        int d = tid & 127;
        int r = tid >> 7;
        double mu = (double)bufB[r * 256 + d];
        double lv = (double)bufB[r * 256 + 128 + d];
        double xv = (double)x2s[r * 128 + d];
        double mx = (double)stat[d];
        double mxsq = (double)stat[128 + d];
        double iv = exp(-lv);
        p = -0.5 * iv * (xv * xv - mxsq - 2.0 * mu * (xv - mx));
    }
#pragma unroll
    for (int off = 32; off > 0; off >>= 1) p += __shfl_down(p, off, 64);
    if (lane == 0) dred[wv] = p;
    __syncthreads();
    if (tid == 0) {
        double s = 0.0;
#pragma unroll
        for (int i = 0; i < 16; i++) s += dred[i];
        atomicAdd(out, (float)(s * (1.0 / 1024.0)));
    }
}

extern "C" void kernel_launch(void* const* d_in, const int* in_sizes, int n_in,
                              void* d_out, int out_size, void* d_ws, size_t ws_size,
                              hipStream_t stream) {
    const float* x1 = (const float*)d_in[0];
    const float* x2 = (const float*)d_in[1];
    const float* W1 = (const float*)d_in[2];
    const float* b1 = (const float*)d_in[3];
    const float* W2 = (const float*)d_in[4];
    const float* b2 = (const float*)d_in[5];
    const float* W3 = (const float*)d_in[6];
    const float* b3 = (const float*)d_in[7];
    float* out = (float*)d_out;
    float* ws = (float*)d_ws;

    stats_kernel<<<8, 256, 0, stream>>>(x2, ws, out);
    club_kernel<<<NBLK, NTHR, 0, stream>>>(x1, x2, W1, b1, W2, b2, W3, b3, ws, out);
}

// Round 4
// 86.017 us; speedup vs baseline: 1.1556x; 1.1556x over previous
//
#include <hip/hip_runtime.h>

#define NR 1024
#define ROWS 4
#define NBLK 256     // 1 block per CU
#define NTHR 1024    // 128 col-pairs x 8 k-octants
#define SBLK 32      // stats blocks

// ---------------- K1: partial column sums of x2 / x2^2 into disjoint ws slots
__global__ __launch_bounds__(256) void stats_kernel(const float* __restrict__ x2,
                                                    float* __restrict__ ws,
                                                    float* __restrict__ out) {
    int tid = threadIdx.x;
    int d = tid & 127;
    int g = tid >> 7;                   // 0/1
    int row0 = blockIdx.x * 32 + g;     // 32 rows per block
    float s = 0.f, s2 = 0.f;
#pragma unroll
    for (int i = 0; i < 16; i++) {
        float v = x2[(row0 + 2 * i) * 128 + d];
        s += v;
        s2 += v * v;
    }
    __shared__ float sh[256], sh2[256];
    sh[tid] = s;
    sh2[tid] = s2;
    __syncthreads();
    if (g == 0) {
        ws[blockIdx.x * 256 + d]       = sh[tid] + sh[tid + 128];
        ws[blockIdx.x * 256 + 128 + d] = sh2[tid] + sh2[tid + 128];
    }
    if (blockIdx.x == 0 && tid == 0) out[0] = 0.f;
}

// ---------------- fused layer: thread (g=col-pair, q=k-octant) computes
// acc[r][c] over k in [32q,32q+32) for 4 rows x 2 cols; LDS k-reduce.
// W loads: lanes are g-consecutive -> 512B contiguous per wave instr (coalesced).
// x loads: wave-uniform ds_read_b128 broadcasts (q uniform per wave).
__device__ __forceinline__ void layer(const float* __restrict__ in_lds,
                                      const float* __restrict__ W,
                                      const float* __restrict__ b,
                                      float* __restrict__ out_lds,
                                      float* __restrict__ red,
                                      int g, int q, int act) {
    float acc[8];   // acc[r*2+c]
#pragma unroll
    for (int e = 0; e < 8; e++) acc[e] = 0.f;
    const float4* in4 = (const float4*)in_lds;
    const float2* Wp = (const float2*)W + g;    // ((float2*)W)[k*128+g] = W[k*256+2g]
    int k0 = q * 32;
#pragma unroll
    for (int j = 0; j < 8; j++) {
        int k = k0 + 4 * j;
        float2 w0 = Wp[(k + 0) * 128];
        float2 w1 = Wp[(k + 1) * 128];
        float2 w2 = Wp[(k + 2) * 128];
        float2 w3 = Wp[(k + 3) * 128];
        float4 xa = in4[0 * 64 + 8 * q + j];
        float4 xb = in4[1 * 64 + 8 * q + j];
        float4 xc = in4[2 * 64 + 8 * q + j];
        float4 xd = in4[3 * 64 + 8 * q + j];
        acc[0] = fmaf(xa.x, w0.x, acc[0]); acc[1] = fmaf(xa.x, w0.y, acc[1]);
        acc[0] = fmaf(xa.y, w1.x, acc[0]); acc[1] = fmaf(xa.y, w1.y, acc[1]);
        acc[0] = fmaf(xa.z, w2.x, acc[0]); acc[1] = fmaf(xa.z, w2.y, acc[1]);
        acc[0] = fmaf(xa.w, w3.x, acc[0]); acc[1] = fmaf(xa.w, w3.y, acc[1]);
        acc[2] = fmaf(xb.x, w0.x, acc[2]); acc[3] = fmaf(xb.x, w0.y, acc[3]);
        acc[2] = fmaf(xb.y, w1.x, acc[2]); acc[3] = fmaf(xb.y, w1.y, acc[3]);
        acc[2] = fmaf(xb.z, w2.x, acc[2]); acc[3] = fmaf(xb.z, w2.y, acc[3]);
        acc[2] = fmaf(xb.w, w3.x, acc[2]); acc[3] = fmaf(xb.w, w3.y, acc[3]);
        acc[4] = fmaf(xc.x, w0.x, acc[4]); acc[5] = fmaf(xc.x, w0.y, acc[5]);
        acc[4] = fmaf(xc.y, w1.x, acc[4]); acc[5] = fmaf(xc.y, w1.y, acc[5]);
        acc[4] = fmaf(xc.z, w2.x, acc[4]); acc[5] = fmaf(xc.z, w2.y, acc[5]);
        acc[4] = fmaf(xc.w, w3.x, acc[4]); acc[5] = fmaf(xc.w, w3.y, acc[5]);
        acc[6] = fmaf(xd.x, w0.x, acc[6]); acc[7] = fmaf(xd.x, w0.y, acc[7]);
        acc[6] = fmaf(xd.y, w1.x, acc[6]); acc[7] = fmaf(xd.y, w1.y, acc[7]);
        acc[6] = fmaf(xd.z, w2.x, acc[6]); acc[7] = fmaf(xd.z, w2.y, acc[7]);
        acc[6] = fmaf(xd.w, w3.x, acc[6]); acc[7] = fmaf(xd.w, w3.y, acc[7]);
    }
    // k-octant reduce: red[q][e][g] (dword addr = q*1024 + e*128 + g), lanes
    // vary g -> consecutive dwords -> conflict-free.
#pragma unroll
    for (int e = 0; e < 8; e++) red[q * 1024 + e * 128 + g] = acc[e];
    __syncthreads();
    float s = 0.f;
#pragma unroll
    for (int q2 = 0; q2 < 8; q2++) s += red[q2 * 1024 + q * 128 + g];
    int r = q >> 1;
    int col = 2 * g + (q & 1);
    float v = s + b[col];
    v = act ? tanhf(v) : fmaxf(v, 0.f);
    out_lds[r * 256 + col] = v;      // stride-2 across lanes: 2-way alias (free)
    __syncthreads();
}

// ---------------- K2: fused 3-layer MLP + CLUB contribution + reduction
__global__ __launch_bounds__(1024, 4) void club_kernel(
    const float* __restrict__ x1, const float* __restrict__ x2,
    const float* __restrict__ W1, const float* __restrict__ b1,
    const float* __restrict__ W2, const float* __restrict__ b2,
    const float* __restrict__ W3, const float* __restrict__ b3,
    const float* __restrict__ part, float* __restrict__ out) {
    __shared__ float bufA[ROWS * 256];
    __shared__ float bufB[ROWS * 256];
    __shared__ float x2s[ROWS * 128];
    __shared__ float stat[256];
    __shared__ float red[8 * 8 * 128];   // 32 KB
    __shared__ double dred[16];

    int tid = threadIdx.x;
    int lane = tid & 63, wv = tid >> 6;
    int g = tid & 127;                   // column pair {2g, 2g+1}
    int q = tid >> 7;                    // k-octant
    int row0 = blockIdx.x * ROWS;

    // prologue: stage x1 (4x256), x2 (4x128); reduce the 32 stats partials
    if (tid < 256) {
        ((float4*)bufA)[tid] = ((const float4*)(x1 + row0 * 256))[tid];
    } else if (tid < 384) {
        ((float4*)x2s)[tid - 256] = ((const float4*)(x2 + row0 * 128))[tid - 256];
    } else if (tid >= 512 && tid < 768) {
        int t = tid - 512;
        float s = 0.f;
#pragma unroll
        for (int p = 0; p < SBLK; p++) s += part[p * 256 + t];
        stat[t] = s * (1.f / 1024.f);
    }
    __syncthreads();

    layer(bufA, W1, b1, bufB, red, g, q, 0);   // h1 = relu(x1@W1+b1)
    layer(bufB, W2, b2, bufA, red, g, q, 0);   // h2 = relu(h1@W2+b2)
    layer(bufA, W3, b3, bufB, red, g, q, 1);   // g  = tanh(h2@W3+b3)

    // pos-neg = -0.5*exp(-lv)*( x2^2 - mxsq - 2*mu*(x2 - mx) )
    double p = 0.0;
    if (tid < 512) {
        int d = tid & 127;
        int r = tid >> 7;
        double mu = (double)bufB[r * 256 + d];
        double lv = (double)bufB[r * 256 + 128 + d];
        double xv = (double)x2s[r * 128 + d];
        double mx = (double)stat[d];
        double mxsq = (double)stat[128 + d];
        double iv = exp(-lv);
        p = -0.5 * iv * (xv * xv - mxsq - 2.0 * mu * (xv - mx));
    }
#pragma unroll
    for (int off = 32; off > 0; off >>= 1) p += __shfl_down(p, off, 64);
    if (lane == 0) dred[wv] = p;
    __syncthreads();
    if (tid == 0) {
        double s = 0.0;
#pragma unroll
        for (int i = 0; i < 16; i++) s += dred[i];
        atomicAdd(out, (float)(s * (1.0 / 1024.0)));
    }
}

extern "C" void kernel_launch(void* const* d_in, const int* in_sizes, int n_in,
                              void* d_out, int out_size, void* d_ws, size_t ws_size,
                              hipStream_t stream) {
    const float* x1 = (const float*)d_in[0];
    const float* x2 = (const float*)d_in[1];
    const float* W1 = (const float*)d_in[2];
    const float* b1 = (const float*)d_in[3];
    const float* W2 = (const float*)d_in[4];
    const float* b2 = (const float*)d_in[5];
    const float* W3 = (const float*)d_in[6];
    const float* b3 = (const float*)d_in[7];
    float* out = (float*)d_out;
    float* ws = (float*)d_ws;

    stats_kernel<<<SBLK, 256, 0, stream>>>(x2, ws, out);
    club_kernel<<<NBLK, NTHR, 0, stream>>>(x1, x2, W1, b1, W2, b2, W3, b3, ws, out);
}

// Round 5
// 82.956 us; speedup vs baseline: 1.1983x; 1.0369x over previous
//
#include <hip/hip_runtime.h>

#define NR 1024
#define ROWS 4
#define NBLK 256     // 1 block per CU
#define NTHR 1024    // 64 col-quads x 16 k-16ths
#define SBLK 32      // stats blocks

// ---------------- K1: partial column sums of x2 / x2^2 into disjoint ws slots
__global__ __launch_bounds__(256) void stats_kernel(const float* __restrict__ x2,
                                                    float* __restrict__ ws,
                                                    float* __restrict__ out) {
    int tid = threadIdx.x;
    int d = tid & 127;
    int g = tid >> 7;                   // 0/1
    int row0 = blockIdx.x * 32 + g;     // 32 rows per block
    float s = 0.f, s2 = 0.f;
#pragma unroll
    for (int i = 0; i < 16; i++) {
        float v = x2[(row0 + 2 * i) * 128 + d];
        s += v;
        s2 += v * v;
    }
    __shared__ float sh[256], sh2[256];
    sh[tid] = s;
    sh2[tid] = s2;
    __syncthreads();
    if (g == 0) {
        ws[blockIdx.x * 256 + d]       = sh[tid] + sh[tid + 128];
        ws[blockIdx.x * 256 + 128 + d] = sh2[tid] + sh2[tid + 128];
    }
    if (blockIdx.x == 0 && tid == 0) out[0] = 0.f;
}

// ---------------- fused layer: thread (lane l, wave q) computes
// acc[r][c] = sum_{k in [16q,16q+16)} x[r][k] * W[k][4l+c], r,c in 0..3.
// W: 16 global dwordx4, lanes contiguous -> 1KB/wave-inst, W read once/block.
// x: 16 wave-uniform ds_read_b128 broadcasts.
// reduce: 4 ds_write_b128 (conflict-free), re-read by waves q<4 as b128.
__device__ __forceinline__ void layer(const float* __restrict__ in_lds,
                                      const float* __restrict__ W,
                                      const float* __restrict__ b,
                                      float* __restrict__ out_lds,
                                      float* __restrict__ red,
                                      int l, int q, int act) {
    float4 acc[4];   // acc[r], components = 4 cols
#pragma unroll
    for (int r = 0; r < 4; r++) acc[r] = make_float4(0.f, 0.f, 0.f, 0.f);
    const float4* in4 = (const float4*)in_lds;
    const float4* Wp = (const float4*)W + l;   // Wp[k*64] = W[k][4l..4l+3]
    int k0 = q * 16;
#pragma unroll
    for (int j = 0; j < 4; j++) {
        float4 w0 = Wp[(k0 + 4 * j + 0) * 64];
        float4 w1 = Wp[(k0 + 4 * j + 1) * 64];
        float4 w2 = Wp[(k0 + 4 * j + 2) * 64];
        float4 w3 = Wp[(k0 + 4 * j + 3) * 64];
#pragma unroll
        for (int r = 0; r < 4; r++) {
            float4 xr = in4[r * 64 + 4 * q + j];   // broadcast
            acc[r].x = fmaf(xr.x, w0.x, acc[r].x); acc[r].y = fmaf(xr.x, w0.y, acc[r].y);
            acc[r].z = fmaf(xr.x, w0.z, acc[r].z); acc[r].w = fmaf(xr.x, w0.w, acc[r].w);
            acc[r].x = fmaf(xr.y, w1.x, acc[r].x); acc[r].y = fmaf(xr.y, w1.y, acc[r].y);
            acc[r].z = fmaf(xr.y, w1.z, acc[r].z); acc[r].w = fmaf(xr.y, w1.w, acc[r].w);
            acc[r].x = fmaf(xr.z, w2.x, acc[r].x); acc[r].y = fmaf(xr.z, w2.y, acc[r].y);
            acc[r].z = fmaf(xr.z, w2.z, acc[r].z); acc[r].w = fmaf(xr.z, w2.w, acc[r].w);
            acc[r].x = fmaf(xr.w, w3.x, acc[r].x); acc[r].y = fmaf(xr.w, w3.y, acc[r].y);
            acc[r].z = fmaf(xr.w, w3.z, acc[r].z); acc[r].w = fmaf(xr.w, w3.w, acc[r].w);
        }
    }
    // red[q][r][l] as float4: consecutive lanes -> conflict-free b128
    float4* red4 = (float4*)red;
#pragma unroll
    for (int r = 0; r < 4; r++) red4[q * 256 + r * 64 + l] = acc[r];
    __syncthreads();
    if (q < 4) {                 // wave q handles row q, cols 4l..4l+3
        float4 s = make_float4(0.f, 0.f, 0.f, 0.f);
#pragma unroll
        for (int q2 = 0; q2 < 16; q2++) {
            float4 v = red4[q2 * 256 + q * 64 + l];
            s.x += v.x; s.y += v.y; s.z += v.z; s.w += v.w;
        }
        float4 bb = ((const float4*)b)[l];
        s.x += bb.x; s.y += bb.y; s.z += bb.z; s.w += bb.w;
        if (act) {
            s.x = tanhf(s.x); s.y = tanhf(s.y); s.z = tanhf(s.z); s.w = tanhf(s.w);
        } else {
            s.x = fmaxf(s.x, 0.f); s.y = fmaxf(s.y, 0.f);
            s.z = fmaxf(s.z, 0.f); s.w = fmaxf(s.w, 0.f);
        }
        ((float4*)out_lds)[q * 64 + l] = s;
    }
    __syncthreads();
}

// ---------------- K2: fused 3-layer MLP + CLUB contribution + reduction
__global__ __launch_bounds__(1024, 4) void club_kernel(
    const float* __restrict__ x1, const float* __restrict__ x2,
    const float* __restrict__ W1, const float* __restrict__ b1,
    const float* __restrict__ W2, const float* __restrict__ b2,
    const float* __restrict__ W3, const float* __restrict__ b3,
    const float* __restrict__ part, float* __restrict__ out) {
    __shared__ float bufA[ROWS * 256];
    __shared__ float bufB[ROWS * 256];
    __shared__ float x2s[ROWS * 128];
    __shared__ float stat[256];
    __shared__ float red[16 * 1024];   // 64 KB k-split partials
    __shared__ double dred[16];

    int tid = threadIdx.x;
    int lane = tid & 63, wv = tid >> 6;
    int row0 = blockIdx.x * ROWS;

    // prologue: stage x1 (4x256), x2 (4x128); reduce the 32 stats partials
    if (tid < 256) {
        ((float4*)bufA)[tid] = ((const float4*)(x1 + row0 * 256))[tid];
    } else if (tid < 384) {
        ((float4*)x2s)[tid - 256] = ((const float4*)(x2 + row0 * 128))[tid - 256];
    } else if (tid >= 512 && tid < 768) {
        int t = tid - 512;
        float s = 0.f;
#pragma unroll
        for (int p = 0; p < SBLK; p++) s += part[p * 256 + t];
        stat[t] = s * (1.f / 1024.f);
    }
    __syncthreads();

    layer(bufA, W1, b1, bufB, red, lane, wv, 0);   // h1 = relu(x1@W1+b1)
    layer(bufB, W2, b2, bufA, red, lane, wv, 0);   // h2 = relu(h1@W2+b2)
    layer(bufA, W3, b3, bufB, red, lane, wv, 1);   // g  = tanh(h2@W3+b3)

    // pos-neg = -0.5*exp(-lv)*( x2^2 - mxsq - 2*mu*(x2 - mx) )
    double p = 0.0;
    if (tid < 512) {
        int d = tid & 127;
        int r = tid >> 7;
        double mu = (double)bufB[r * 256 + d];
        double lv = (double)bufB[r * 256 + 128 + d];
        double xv = (double)x2s[r * 128 + d];
        double mx = (double)stat[d];
        double mxsq = (double)stat[128 + d];
        double iv = exp(-lv);
        p = -0.5 * iv * (xv * xv - mxsq - 2.0 * mu * (xv - mx));
    }
#pragma unroll
    for (int off = 32; off > 0; off >>= 1) p += __shfl_down(p, off, 64);
    if (lane == 0) dred[wv] = p;
    __syncthreads();
    if (tid == 0) {
        double s = 0.0;
#pragma unroll
        for (int i = 0; i < 16; i++) s += dred[i];
        atomicAdd(out, (float)(s * (1.0 / 1024.0)));
    }
}

extern "C" void kernel_launch(void* const* d_in, const int* in_sizes, int n_in,
                              void* d_out, int out_size, void* d_ws, size_t ws_size,
                              hipStream_t stream) {
    const float* x1 = (const float*)d_in[0];
    const float* x2 = (const float*)d_in[1];
    const float* W1 = (const float*)d_in[2];
    const float* b1 = (const float*)d_in[3];
    const float* W2 = (const float*)d_in[4];
    const float* b2 = (const float*)d_in[5];
    const float* W3 = (const float*)d_in[6];
    const float* b3 = (const float*)d_in[7];
    float* out = (float*)d_out;
    float* ws = (float*)d_ws;

    stats_kernel<<<SBLK, 256, 0, stream>>>(x2, ws, out);
    club_kernel<<<NBLK, NTHR, 0, stream>>>(x1, x2, W1, b1, W2, b2, W3, b3, ws, out);
}